// Round 11
// baseline (626.367 us; speedup 1.0000x reference)
//
#include <hip/hip_runtime.h>

#define N_SRC   100000
#define N_DST   50000
#define N_EDGES 600000
#define D       128
#define RPB     16    // dst rows per block (fallback GEMM)
#define PAD     48    // fallback padded CSR slots per dst
#define NTILES  (N_DST / 16)   // 3125
#define TPAD    288   // slots per 16-row tile (Poisson(192) + 6.9 sigma)

#define CONV_BLOCKS  ((N_SRC * D / 4) / 256)          // 12500 (4 f32/thread)
#define MISC_ELEMS   (2 * D * D + N_DST + D)          // Wt + cnt + zero-row
#define MISC_BLOCKS  ((MISC_ELEMS + 255) / 256)
#define FILL_BLOCKS  ((N_EDGES + 255) / 256)          // 2344

typedef short bf16x8 __attribute__((ext_vector_type(8)));
typedef float f32x4  __attribute__((ext_vector_type(4)));

static __device__ __forceinline__ unsigned short f2bf(float f) {
    unsigned u = __float_as_uint(f);
    u += 0x7FFF + ((u >> 16) & 1);  // RNE
    return (unsigned short)(u >> 16);
}
static __device__ __forceinline__ unsigned pk(float a, float b) {
    return (unsigned)f2bf(a) | ((unsigned)f2bf(b) << 16);
}
// 8 LDS f32 atomic adds (ds_add_f32, no-return) from 8 packed bf16
static __device__ __forceinline__ void atomic8(float* a, uint4 u) {
    atomicAdd(a + 0, __uint_as_float(u.x << 16));
    atomicAdd(a + 1, __uint_as_float(u.x & 0xFFFF0000u));
    atomicAdd(a + 2, __uint_as_float(u.y << 16));
    atomicAdd(a + 3, __uint_as_float(u.y & 0xFFFF0000u));
    atomicAdd(a + 4, __uint_as_float(u.z << 16));
    atomicAdd(a + 5, __uint_as_float(u.z & 0xFFFF0000u));
    atomicAdd(a + 6, __uint_as_float(u.w << 16));
    atomicAdd(a + 7, __uint_as_float(u.w & 0xFFFF0000u));
}

// ---- 1. prep: src f32->bf16 + W transpose + zero counters + zero-row ----
__global__ __launch_bounds__(256) void prep_kernel(
    const float* __restrict__ src_rep, unsigned short* __restrict__ srcb,
    const float* __restrict__ W, unsigned short* __restrict__ Wt,
    int* __restrict__ cnt) {
    if (blockIdx.x < CONV_BLOCKS) {
        size_t t = (size_t)blockIdx.x * 256 + threadIdx.x;  // 4 f32 -> 4 bf16
        float4 v = reinterpret_cast<const float4*>(src_rep)[t];
        uint2 w;
        w.x = pk(v.x, v.y); w.y = pk(v.z, v.w);
        reinterpret_cast<uint2*>(srcb)[t] = w;
    } else {
        int t = (blockIdx.x - CONV_BLOCKS) * 256 + threadIdx.x;
        if (t < 2 * D * D) {
            int n = t >> 8, k = t & 255;
            Wt[n * 256 + k] = f2bf(W[(size_t)k * D + n]);
        }
        int c = t - 2 * D * D;
        if (c >= 0 && c < N_DST) cnt[c] = 0;   // covers NTILES too
        int z = c - N_DST;
        if (z >= 0 && z < D) srcb[(size_t)N_SRC * D + z] = 0;  // zero row
    }
}

// ---- 2. fill tile-CSR: tile_perm[t*TPAD+pos] = src | (localrow<<20) ----
__global__ __launch_bounds__(256) void fill_kernel(
    const int* __restrict__ edge_src, const int* __restrict__ edge_dst,
    int* __restrict__ tile_cnt, unsigned* __restrict__ tile_perm) {
    int e = blockIdx.x * 256 + threadIdx.x;
    if (e < N_EDGES) {
        int d = edge_dst[e];
        int t = d >> 4, lr = d & 15;
        int pos = atomicAdd(&tile_cnt[t], 1);
        if (pos < TPAD)
            tile_perm[(size_t)t * TPAD + pos] = (unsigned)edge_src[e] | ((unsigned)lr << 20);
    }
}

// ---- 3. fused edge-centric gather + MFMA GEMM + relu ----
// 512 threads = 8 waves = 32 quarter-waves; block owns 16 dst rows.
// Quarter g processes 4 independent edges/iter: entry(4B broadcast) ->
// row load (16B/lane) -> unpack -> LDS f32 atomicAdd into fagg[lr][].
// No shuffles, no per-row chains; invalid slots hit the zero row.
__global__ __launch_bounds__(512) void fused_kernel(
    const unsigned short* __restrict__ srcb,   // [N_SRC+1][D] bf16 (last row 0)
    const float* __restrict__ dst_rep,
    const int*   __restrict__ tile_cnt,
    const unsigned* __restrict__ tile_perm,
    const unsigned short* __restrict__ Wt,     // [D][2*D] bf16, k-contiguous
    const float* __restrict__ bias,
    float*       __restrict__ out) {
    __shared__ float fagg[16][132];            // stride 132: bank spread
    __shared__ unsigned short Abf[16 * 256];   // swizzled bf16 A-tile
    const int row0 = blockIdx.x * 16;
    const int tid = threadIdx.x, lane = tid & 63, wave = tid >> 6;

    // zero fagg
    for (int i = tid; i < 16 * 132; i += 512)
        ((float*)fagg)[i] = 0.f;
    // stage dst_rep -> bf16, k in [0,128)
    if (tid < 256) {
        int r = tid >> 4, b = tid & 15;
        const float4* p = reinterpret_cast<const float4*>(
            dst_rep + (size_t)(row0 + r) * D + b * 8);
        float4 v0 = p[0], v1 = p[1];
        uint4 w;
        w.x = pk(v0.x, v0.y); w.y = pk(v0.z, v0.w);
        w.z = pk(v1.x, v1.y); w.w = pk(v1.z, v1.w);
        *reinterpret_cast<uint4*>(&Abf[r * 256 + (b ^ (r & 7)) * 8]) = w;
    }
    __syncthreads();

    // edge loop
    const int g = tid >> 4, cl = tid & 15;
    const int tcnt = min(tile_cnt[blockIdx.x], TPAD);
    const unsigned* tp = tile_perm + (size_t)blockIdx.x * TPAD;
    const unsigned ZE = (unsigned)N_SRC;  // zero-row entry (lr=0)
    const int tm1 = tcnt - 1;
    for (int i0 = 0; i0 < tcnt; i0 += 128) {  // block-uniform bound
        const int ia = i0 + g, ib = ia + 32, ic = ia + 64, id = ia + 96;
        unsigned eA = tp[min(ia, tm1)]; eA = (ia <= tm1) ? eA : ZE;
        unsigned eB = tp[min(ib, tm1)]; eB = (ib <= tm1) ? eB : ZE;
        unsigned eC = tp[min(ic, tm1)]; eC = (ic <= tm1) ? eC : ZE;
        unsigned eD = tp[min(id, tm1)]; eD = (id <= tm1) ? eD : ZE;
        const uint4 uA = *reinterpret_cast<const uint4*>(srcb + (size_t)(eA & 0xFFFFFu) * D + cl * 8);
        const uint4 uB = *reinterpret_cast<const uint4*>(srcb + (size_t)(eB & 0xFFFFFu) * D + cl * 8);
        const uint4 uC = *reinterpret_cast<const uint4*>(srcb + (size_t)(eC & 0xFFFFFu) * D + cl * 8);
        const uint4 uD = *reinterpret_cast<const uint4*>(srcb + (size_t)(eD & 0xFFFFFu) * D + cl * 8);
        atomic8(&fagg[eA >> 20][cl * 8], uA);
        atomic8(&fagg[eB >> 20][cl * 8], uB);
        atomic8(&fagg[eC >> 20][cl * 8], uC);
        atomic8(&fagg[eD >> 20][cl * 8], uD);
    }
    __syncthreads();

    // convert fagg f32 -> swizzled bf16 A-tile, k in [128,256)
    {
        int r = tid >> 5;            // 0..15
        int p = (tid & 31) * 4;      // f32 pos 0..124
        float f0 = fagg[r][p], f1 = fagg[r][p + 1];
        float f2 = fagg[r][p + 2], f3 = fagg[r][p + 3];
        uint2 w; w.x = pk(f0, f1); w.y = pk(f2, f3);
        int b = 16 + (p >> 3);
        *reinterpret_cast<uint2*>(&Abf[r * 256 + (b ^ (r & 7)) * 8 + (p & 7)]) = w;
    }
    __syncthreads();

    // MFMA: A 16x256 (LDS) x B 256x16 per wave; wave w -> out cols [16w,16w+16)
    f32x4 c0 = {0.f, 0.f, 0.f, 0.f};
    const int ar = lane & 15;
    const int kb = lane >> 4;
    const int n0 = wave * 16 + (lane & 15);
#pragma unroll
    for (int s = 0; s < 8; ++s) {
        int b = s * 4 + kb;
        bf16x8 af = *reinterpret_cast<const bf16x8*>(&Abf[ar * 256 + (b ^ (ar & 7)) * 8]);
        bf16x8 b0 = *reinterpret_cast<const bf16x8*>(&Wt[(size_t)n0 * 256 + s * 32 + kb * 8]);
        c0 = __builtin_amdgcn_mfma_f32_16x16x32_bf16(af, b0, c0, 0, 0, 0);
    }

    const float bv = bias[n0];
#pragma unroll
    for (int g2 = 0; g2 < 4; ++g2) {
        size_t orow = row0 + (lane >> 4) * 4 + g2;
        out[orow * D + n0] = fmaxf(c0[g2] + bv, 0.f);
    }
}

// ---- fallback path (small ws): round-6 verified kernels ----
__global__ __launch_bounds__(256) void prep_small_kernel(
    const float* __restrict__ W, unsigned short* __restrict__ Wt,
    int* __restrict__ cnt) {
    int t = blockIdx.x * 256 + threadIdx.x;
    if (t < 2 * D * D) {
        int n = t >> 8, k = t & 255;
        Wt[n * 256 + k] = f2bf(W[(size_t)k * D + n]);
    }
    int c = t - 2 * D * D;
    if (c >= 0 && c < N_DST) cnt[c] = 0;
}

__global__ __launch_bounds__(256) void fill_small_kernel(
    const int* __restrict__ edge_src, const int* __restrict__ edge_dst,
    int* __restrict__ cnt, int* __restrict__ perm) {
    int e = blockIdx.x * 256 + threadIdx.x;
    if (e < N_EDGES) {
        int d = edge_dst[e];
        int pos = atomicAdd(&cnt[d], 1);
        if (pos < PAD) perm[d * PAD + pos] = edge_src[e];
    }
}

__global__ __launch_bounds__(256) void gather_f32_kernel(
    const float* __restrict__ src_rep,
    const int*   __restrict__ cnt,
    const int*   __restrict__ perm,
    unsigned short* __restrict__ agg) {
    const int tid = threadIdx.x, lane = tid & 63, wave = tid >> 6;
    const int h = lane >> 5, c = lane & 31;
    const int dn = blockIdx.x * 4 + wave;
    const int deg = min(cnt[dn], PAD);
    const int pi = perm[(size_t)dn * PAD + min(lane, PAD - 1)];

    f32x4 a0 = {0.f, 0.f, 0.f, 0.f}, a1 = a0, a2 = a0, a3 = a0;
    const int dm1 = deg - 1;
    for (int base = 0; base < deg; base += 8) {
        int e0 = base + h, e1 = base + 2 + h, e2 = base + 4 + h, e3 = base + 6 + h;
        int s0 = __shfl(pi, min(e0, max(dm1, 0)));
        int s1 = __shfl(pi, min(e1, max(dm1, 0)));
        int s2 = __shfl(pi, min(e2, max(dm1, 0)));
        int s3 = __shfl(pi, min(e3, max(dm1, 0)));
        if (e0 <= dm1) a0 += *reinterpret_cast<const f32x4*>(src_rep + (size_t)s0 * D + c * 4);
        if (e1 <= dm1) a1 += *reinterpret_cast<const f32x4*>(src_rep + (size_t)s1 * D + c * 4);
        if (e2 <= dm1) a2 += *reinterpret_cast<const f32x4*>(src_rep + (size_t)s2 * D + c * 4);
        if (e3 <= dm1) a3 += *reinterpret_cast<const f32x4*>(src_rep + (size_t)s3 * D + c * 4);
    }
    a0 += a1; a2 += a3; a0 += a2;
#pragma unroll
    for (int qq = 0; qq < 4; ++qq) a0[qq] += __shfl_xor(a0[qq], 32);
    if (h == 0) {
        uint2 w;
        w.x = pk(a0[0], a0[1]); w.y = pk(a0[2], a0[3]);
        *reinterpret_cast<uint2*>(agg + (size_t)dn * D + c * 4) = w;
    }
}

__global__ __launch_bounds__(256) void gemm_kernel(
    const float* __restrict__ dst_rep,
    const unsigned short* __restrict__ agg,
    const unsigned short* __restrict__ Wt,
    const float* __restrict__ bias,
    float*       __restrict__ out) {
    __shared__ unsigned short Abf[RPB * 2 * D];
    const int row0 = blockIdx.x * RPB;
    const int tid = threadIdx.x, lane = tid & 63, wave = tid >> 6;
    {
        int r = tid >> 4, b = tid & 15;
        const float4* p = reinterpret_cast<const float4*>(
            dst_rep + (size_t)(row0 + r) * D + b * 8);
        float4 v0 = p[0], v1 = p[1];
        uint4 w;
        w.x = pk(v0.x, v0.y); w.y = pk(v0.z, v0.w);
        w.z = pk(v1.x, v1.y); w.w = pk(v1.z, v1.w);
        *reinterpret_cast<uint4*>(&Abf[r * 256 + (b ^ (r & 7)) * 8]) = w;
        uint4 g = *reinterpret_cast<const uint4*>(agg + (size_t)(row0 + r) * D + b * 8);
        *reinterpret_cast<uint4*>(&Abf[r * 256 + ((16 + b) ^ (r & 7)) * 8]) = g;
    }
    __syncthreads();

    f32x4 c0 = {0.f, 0.f, 0.f, 0.f}, c1 = {0.f, 0.f, 0.f, 0.f};
    const int ar = lane & 15;
    const int kb = lane >> 4;
    const int n0 = wave * 32 + (lane & 15);
#pragma unroll
    for (int s = 0; s < 8; ++s) {
        int b = s * 4 + kb;
        bf16x8 af = *reinterpret_cast<const bf16x8*>(&Abf[ar * 256 + (b ^ (ar & 7)) * 8]);
        int kbase = s * 32 + kb * 8;
        bf16x8 b0 = *reinterpret_cast<const bf16x8*>(&Wt[(size_t)n0 * 256 + kbase]);
        bf16x8 b1 = *reinterpret_cast<const bf16x8*>(&Wt[(size_t)(n0 + 16) * 256 + kbase]);
        c0 = __builtin_amdgcn_mfma_f32_16x16x32_bf16(af, b0, c0, 0, 0, 0);
        c1 = __builtin_amdgcn_mfma_f32_16x16x32_bf16(af, b1, c1, 0, 0, 0);
    }
    const float bv0 = bias[wave * 32 + (lane & 15)];
    const float bv1 = bias[wave * 32 + 16 + (lane & 15)];
#pragma unroll
    for (int g = 0; g < 4; ++g) {
        size_t orow = row0 + (lane >> 4) * 4 + g;
        out[orow * D + wave * 32 + (lane & 15)]      = fmaxf(c0[g] + bv0, 0.f);
        out[orow * D + wave * 32 + 16 + (lane & 15)] = fmaxf(c1[g] + bv1, 0.f);
    }
}

extern "C" void kernel_launch(void* const* d_in, const int* in_sizes, int n_in,
                              void* d_out, int out_size, void* d_ws, size_t ws_size,
                              hipStream_t stream) {
    const float* src_rep  = (const float*)d_in[0];
    const float* dst_rep  = (const float*)d_in[1];
    const int*   edge_src = (const int*)d_in[2];
    const int*   edge_dst = (const int*)d_in[3];
    const float* W        = (const float*)d_in[4];
    const float* bias     = (const float*)d_in[5];
    float*       out      = (float*)d_out;

    // ws: cnt[N_DST] | perm-region[N_DST*PAD] | Wt[2*D*D] | {srcb[(N_SRC+1)*D] or agg}
    // main path overlays: tile_cnt -> cnt region, tile_perm -> perm region
    int* cnt  = (int*)d_ws;
    int* perm = cnt + N_DST;
    size_t wt_off = (((size_t)N_DST * (1 + PAD) * 4 + 255) / 256) * 256;
    unsigned short* Wt   = (unsigned short*)((char*)d_ws + wt_off);
    unsigned short* big  = Wt + (size_t)2 * D * D;   // srcb or agg
    const size_t need_full = wt_off + ((size_t)2 * D * D + (size_t)(N_SRC + 1) * D)
                             * sizeof(unsigned short);

    if (ws_size >= need_full) {
        unsigned short* srcb = big;
        prep_kernel<<<CONV_BLOCKS + MISC_BLOCKS, 256, 0, stream>>>(
            src_rep, srcb, W, Wt, cnt);
        fill_kernel<<<FILL_BLOCKS, 256, 0, stream>>>(
            edge_src, edge_dst, cnt, (unsigned*)perm);
        fused_kernel<<<NTILES, 512, 0, stream>>>(
            srcb, dst_rep, cnt, (const unsigned*)perm, Wt, bias, out);
    } else {
        unsigned short* agg = big;
        prep_small_kernel<<<MISC_BLOCKS, 256, 0, stream>>>(W, Wt, cnt);
        fill_small_kernel<<<FILL_BLOCKS, 256, 0, stream>>>(edge_src, edge_dst, cnt, perm);
        gather_f32_kernel<<<N_DST / 4, 256, 0, stream>>>(src_rep, cnt, perm, agg);
        gemm_kernel<<<N_DST / RPB, 256, 0, stream>>>(dst_rep, agg, Wt, bias, out);
    }
}

// Round 12
// 106.689 us; speedup vs baseline: 5.8710x; 5.8710x over previous
//
#include <hip/hip_runtime.h>

#define N_SRC   100000
#define N_DST   50000
#define N_EDGES 600000
#define D       128
#define RPB     16    // dst rows per block in GEMM
#define PAD     48    // padded CSR slots per dst (verified r4-r10: no overflow)

#define CONV_BLOCKS  ((N_SRC * D / 4) / 256)          // 12500 (4 f32/thread)
#define MISC_ELEMS   (2 * D * D + N_DST + D)          // Wt + cnt + zero-row
#define MISC_BLOCKS  ((MISC_ELEMS + 255) / 256)
#define FILL_BLOCKS  ((N_EDGES + 255) / 256)          // 2344

typedef short bf16x8 __attribute__((ext_vector_type(8)));
typedef float f32x4  __attribute__((ext_vector_type(4)));

static __device__ __forceinline__ unsigned short f2bf(float f) {
    unsigned u = __float_as_uint(f);
    u += 0x7FFF + ((u >> 16) & 1);  // RNE
    return (unsigned short)(u >> 16);
}
static __device__ __forceinline__ unsigned pk(float a, float b) {
    return (unsigned)f2bf(a) | ((unsigned)f2bf(b) << 16);
}
// accumulate 8 bf16 (uint4) into 8 f32
static __device__ __forceinline__ void addpk(float* a, uint4 u) {
    a[0] += __uint_as_float(u.x << 16);
    a[1] += __uint_as_float(u.x & 0xFFFF0000u);
    a[2] += __uint_as_float(u.y << 16);
    a[3] += __uint_as_float(u.y & 0xFFFF0000u);
    a[4] += __uint_as_float(u.z << 16);
    a[5] += __uint_as_float(u.z & 0xFFFF0000u);
    a[6] += __uint_as_float(u.w << 16);
    a[7] += __uint_as_float(u.w & 0xFFFF0000u);
}

// ---- 1. prep: src f32->bf16 + W transpose + zero cnt + zero-row ----
__global__ __launch_bounds__(256) void prep_kernel(
    const float* __restrict__ src_rep, unsigned short* __restrict__ srcb,
    const float* __restrict__ W, unsigned short* __restrict__ Wt,
    int* __restrict__ cnt) {
    if (blockIdx.x < CONV_BLOCKS) {
        size_t t = (size_t)blockIdx.x * 256 + threadIdx.x;  // 4 f32 -> 4 bf16
        float4 v = reinterpret_cast<const float4*>(src_rep)[t];
        uint2 w;
        w.x = pk(v.x, v.y); w.y = pk(v.z, v.w);
        reinterpret_cast<uint2*>(srcb)[t] = w;
    } else {
        int t = (blockIdx.x - CONV_BLOCKS) * 256 + threadIdx.x;
        if (t < 2 * D * D) {
            int n = t >> 8, k = t & 255;
            Wt[n * 256 + k] = f2bf(W[(size_t)k * D + n]);
        }
        int c = t - 2 * D * D;
        if (c >= 0 && c < N_DST) cnt[c] = 0;
        int z = c - N_DST;
        if (z >= 0 && z < D) srcb[(size_t)N_SRC * D + z] = 0;  // zero row
    }
}

// ---- 2. fill padded CSR: perm[d*PAD + slot] = src ----
__global__ __launch_bounds__(256) void fill_kernel(
    const int* __restrict__ edge_src, const int* __restrict__ edge_dst,
    int* __restrict__ cnt, int* __restrict__ perm) {
    int e = blockIdx.x * 256 + threadIdx.x;
    if (e < N_EDGES) {
        int d = edge_dst[e];
        int pos = atomicAdd(&cnt[d], 1);
        if (pos < PAD) perm[d * PAD + pos] = edge_src[e];
    }
}

// ---- 3. gather via global_load_lds DMA staging ----
// 256 threads = 4 waves; wave = 1 dst row; NO barriers (each wave reads only
// its own staging). Per 16-edge round: 4 global_load_lds (4 edges x 256B
// each, per-lane global addr, zero VGPR for in-flight data) -> vmcnt(0) ->
// 4 ds_read_b128 + unpack-accumulate. Invalid slots redirect to zero row.
__global__ __launch_bounds__(256) void gather_lds_kernel(
    const unsigned short* __restrict__ srcb,   // [N_SRC+1][D] bf16 (last row 0)
    const int* __restrict__ cnt,
    const int* __restrict__ perm,
    unsigned short* __restrict__ agg) {        // [N_DST][D] bf16
    __shared__ __align__(16) unsigned short stage[4][2048];  // 4KB/wave
    const int tid = threadIdx.x, lane = tid & 63, wave = tid >> 6;
    const int q = lane >> 4, cl = lane & 15;
    const int dn = blockIdx.x * 4 + wave;
    const int deg = min(cnt[dn], PAD);
    const int pi = perm[(size_t)dn * PAD + min(lane, PAD - 1)];
    const int dm = deg - 1, dc = max(dm, 0);
    unsigned short* st = stage[wave];

    float acc0[8] = {}, acc1[8] = {};
    for (int base = 0; base < deg; base += 16) {  // deg wave-uniform
        // issue 4 DMA loads; instr k stages edges base+4k..+3 at st+k*1KB
#pragma unroll
        for (int k = 0; k < 4; ++k) {
            int e = base + 4 * k + q;
            int row = __shfl(pi, min(e, dc));      // full-exec shfl, clamped
            row = (e <= dm) ? row : N_SRC;         // invalid -> zero row
            __builtin_amdgcn_global_load_lds(
                (const unsigned int*)(srcb + (size_t)row * D + cl * 8),
                (unsigned int*)(st + k * 512), 16, 0, 0);
        }
        asm volatile("s_waitcnt vmcnt(0)" ::: "memory");
        __builtin_amdgcn_sched_barrier(0);
        // lane (q,cl): slice cl of edges base+4k+q, k=0..3
#pragma unroll
        for (int k = 0; k < 4; ++k) {
            uint4 u = *reinterpret_cast<const uint4*>(st + k * 512 + q * 128 + cl * 8);
            addpk((k & 1) ? acc1 : acc0, u);
        }
        // fence staging WAR before next round's DMA overwrites it
        asm volatile("s_waitcnt lgkmcnt(0)" ::: "memory");
        __builtin_amdgcn_sched_barrier(0);
    }

#pragma unroll
    for (int i = 0; i < 8; ++i) {
        float s = acc0[i] + acc1[i];
        s += __shfl_xor(s, 16);
        s += __shfl_xor(s, 32);
        acc0[i] = s;
    }
    if (lane < 16) {
        uint4 w;
        w.x = pk(acc0[0], acc0[1]); w.y = pk(acc0[2], acc0[3]);
        w.z = pk(acc0[4], acc0[5]); w.w = pk(acc0[6], acc0[7]);
        *reinterpret_cast<uint4*>(agg + (size_t)dn * D + cl * 8) = w;
    }
}

// ---- 4. GEMM: out = relu([dst_rep|agg] @ W + b) via bf16 MFMA (r6-verified) ----
__global__ __launch_bounds__(256) void gemm_kernel(
    const float* __restrict__ dst_rep,
    const unsigned short* __restrict__ agg,
    const unsigned short* __restrict__ Wt,   // [D][2*D] bf16, k-contiguous
    const float* __restrict__ bias,
    float*       __restrict__ out) {
    __shared__ unsigned short Abf[RPB * 2 * D];  // 8 KiB
    const int row0 = blockIdx.x * RPB;
    const int tid = threadIdx.x, lane = tid & 63, wave = tid >> 6;
    {
        int r = tid >> 4, b = tid & 15;
        const float4* p = reinterpret_cast<const float4*>(
            dst_rep + (size_t)(row0 + r) * D + b * 8);
        float4 v0 = p[0], v1 = p[1];
        uint4 w;
        w.x = pk(v0.x, v0.y); w.y = pk(v0.z, v0.w);
        w.z = pk(v1.x, v1.y); w.w = pk(v1.z, v1.w);
        *reinterpret_cast<uint4*>(&Abf[r * 256 + (b ^ (r & 7)) * 8]) = w;
        uint4 g = *reinterpret_cast<const uint4*>(agg + (size_t)(row0 + r) * D + b * 8);
        *reinterpret_cast<uint4*>(&Abf[r * 256 + ((16 + b) ^ (r & 7)) * 8]) = g;
    }
    __syncthreads();

    f32x4 c0 = {0.f, 0.f, 0.f, 0.f}, c1 = {0.f, 0.f, 0.f, 0.f};
    const int ar = lane & 15;
    const int kb = lane >> 4;
    const int n0 = wave * 32 + (lane & 15);
#pragma unroll
    for (int s = 0; s < 8; ++s) {
        int b = s * 4 + kb;
        bf16x8 af = *reinterpret_cast<const bf16x8*>(&Abf[ar * 256 + (b ^ (ar & 7)) * 8]);
        int kbase = s * 32 + kb * 8;
        bf16x8 b0 = *reinterpret_cast<const bf16x8*>(&Wt[(size_t)n0 * 256 + kbase]);
        bf16x8 b1 = *reinterpret_cast<const bf16x8*>(&Wt[(size_t)(n0 + 16) * 256 + kbase]);
        c0 = __builtin_amdgcn_mfma_f32_16x16x32_bf16(af, b0, c0, 0, 0, 0);
        c1 = __builtin_amdgcn_mfma_f32_16x16x32_bf16(af, b1, c1, 0, 0, 0);
    }
    const float bv0 = bias[wave * 32 + (lane & 15)];
    const float bv1 = bias[wave * 32 + 16 + (lane & 15)];
#pragma unroll
    for (int g = 0; g < 4; ++g) {
        size_t orow = row0 + (lane >> 4) * 4 + g;
        out[orow * D + wave * 32 + (lane & 15)]      = fmaxf(c0[g] + bv0, 0.f);
        out[orow * D + wave * 32 + 16 + (lane & 15)] = fmaxf(c1[g] + bv1, 0.f);
    }
}

// ---- fallback path (small ws): round-6 verified kernels ----
__global__ __launch_bounds__(256) void prep_small_kernel(
    const float* __restrict__ W, unsigned short* __restrict__ Wt,
    int* __restrict__ cnt) {
    int t = blockIdx.x * 256 + threadIdx.x;
    if (t < 2 * D * D) {
        int n = t >> 8, k = t & 255;
        Wt[n * 256 + k] = f2bf(W[(size_t)k * D + n]);
    }
    int c = t - 2 * D * D;
    if (c >= 0 && c < N_DST) cnt[c] = 0;
}

__global__ __launch_bounds__(256) void gather_f32_kernel(
    const float* __restrict__ src_rep,
    const int*   __restrict__ cnt,
    const int*   __restrict__ perm,
    unsigned short* __restrict__ agg) {
    const int tid = threadIdx.x, lane = tid & 63, wave = tid >> 6;
    const int h = lane >> 5, c = lane & 31;
    const int dn = blockIdx.x * 4 + wave;
    const int deg = min(cnt[dn], PAD);
    const int pi = perm[(size_t)dn * PAD + min(lane, PAD - 1)];

    f32x4 a0 = {0.f, 0.f, 0.f, 0.f}, a1 = a0, a2 = a0, a3 = a0;
    const int dm1 = deg - 1;
    for (int base = 0; base < deg; base += 8) {
        int e0 = base + h, e1 = base + 2 + h, e2 = base + 4 + h, e3 = base + 6 + h;
        int s0 = __shfl(pi, min(e0, max(dm1, 0)));
        int s1 = __shfl(pi, min(e1, max(dm1, 0)));
        int s2 = __shfl(pi, min(e2, max(dm1, 0)));
        int s3 = __shfl(pi, min(e3, max(dm1, 0)));
        if (e0 <= dm1) a0 += *reinterpret_cast<const f32x4*>(src_rep + (size_t)s0 * D + c * 4);
        if (e1 <= dm1) a1 += *reinterpret_cast<const f32x4*>(src_rep + (size_t)s1 * D + c * 4);
        if (e2 <= dm1) a2 += *reinterpret_cast<const f32x4*>(src_rep + (size_t)s2 * D + c * 4);
        if (e3 <= dm1) a3 += *reinterpret_cast<const f32x4*>(src_rep + (size_t)s3 * D + c * 4);
    }
    a0 += a1; a2 += a3; a0 += a2;
#pragma unroll
    for (int qq = 0; qq < 4; ++qq) a0[qq] += __shfl_xor(a0[qq], 32);
    if (h == 0) {
        uint2 w;
        w.x = pk(a0[0], a0[1]); w.y = pk(a0[2], a0[3]);
        *reinterpret_cast<uint2*>(agg + (size_t)dn * D + c * 4) = w;
    }
}

extern "C" void kernel_launch(void* const* d_in, const int* in_sizes, int n_in,
                              void* d_out, int out_size, void* d_ws, size_t ws_size,
                              hipStream_t stream) {
    const float* src_rep  = (const float*)d_in[0];
    const float* dst_rep  = (const float*)d_in[1];
    const int*   edge_src = (const int*)d_in[2];
    const int*   edge_dst = (const int*)d_in[3];
    const float* W        = (const float*)d_in[4];
    const float* bias     = (const float*)d_in[5];
    float*       out      = (float*)d_out;

    // ws: cnt[N_DST] | perm[N_DST*PAD] | Wt[2*D*D] | agg[N_DST*D] | srcb[(N_SRC+1)*D]
    int* cnt  = (int*)d_ws;
    int* perm = cnt + N_DST;
    size_t wt_off = (((size_t)N_DST * (1 + PAD) * 4 + 255) / 256) * 256;
    unsigned short* Wt   = (unsigned short*)((char*)d_ws + wt_off);
    unsigned short* agg  = Wt + (size_t)2 * D * D;
    unsigned short* srcb = agg + (size_t)N_DST * D;
    const size_t need_full = wt_off + ((size_t)2 * D * D + (size_t)N_DST * D
                             + (size_t)(N_SRC + 1) * D) * sizeof(unsigned short);

    if (ws_size >= need_full) {
        prep_kernel<<<CONV_BLOCKS + MISC_BLOCKS, 256, 0, stream>>>(
            src_rep, srcb, W, Wt, cnt);
        fill_kernel<<<FILL_BLOCKS, 256, 0, stream>>>(edge_src, edge_dst, cnt, perm);
        gather_lds_kernel<<<N_DST / 4, 256, 0, stream>>>(srcb, cnt, perm, agg);
        gemm_kernel<<<N_DST / RPB, 256, 0, stream>>>(dst_rep, agg, Wt, bias, out);
    } else {
        prep_small_kernel<<<MISC_BLOCKS, 256, 0, stream>>>(W, Wt, cnt);
        fill_kernel<<<FILL_BLOCKS, 256, 0, stream>>>(edge_src, edge_dst, cnt, perm);
        gather_f32_kernel<<<N_DST / 4, 256, 0, stream>>>(src_rep, cnt, perm, agg);
        gemm_kernel<<<N_DST / RPB, 256, 0, stream>>>(dst_rep, agg, Wt, bias, out);
    }
}

// Round 13
// 100.624 us; speedup vs baseline: 6.2248x; 1.0603x over previous
//
#include <hip/hip_runtime.h>

#define N_SRC   100000
#define N_DST   50000
#define N_EDGES 600000
#define D       128
#define RPB     16    // dst rows per block (fallback GEMM)
#define PAD     48    // padded CSR slots per dst (verified r4-r12: no overflow)

#define CONV_BLOCKS  ((N_SRC * D / 4) / 256)          // 12500 (4 f32/thread)
#define MISC_ELEMS   (2 * D * D + N_DST + D)          // Wt + cnt + zero-row
#define MISC_BLOCKS  ((MISC_ELEMS + 255) / 256)
#define FILL_BLOCKS  ((N_EDGES + 255) / 256)          // 2344

typedef short bf16x8 __attribute__((ext_vector_type(8)));
typedef float f32x4  __attribute__((ext_vector_type(4)));

static __device__ __forceinline__ unsigned short f2bf(float f) {
    unsigned u = __float_as_uint(f);
    u += 0x7FFF + ((u >> 16) & 1);  // RNE
    return (unsigned short)(u >> 16);
}
static __device__ __forceinline__ unsigned pk(float a, float b) {
    return (unsigned)f2bf(a) | ((unsigned)f2bf(b) << 16);
}
// accumulate 8 bf16 (uint4) into 8 f32
static __device__ __forceinline__ void addpk(float* a, uint4 u) {
    a[0] += __uint_as_float(u.x << 16);
    a[1] += __uint_as_float(u.x & 0xFFFF0000u);
    a[2] += __uint_as_float(u.y << 16);
    a[3] += __uint_as_float(u.y & 0xFFFF0000u);
    a[4] += __uint_as_float(u.z << 16);
    a[5] += __uint_as_float(u.z & 0xFFFF0000u);
    a[6] += __uint_as_float(u.w << 16);
    a[7] += __uint_as_float(u.w & 0xFFFF0000u);
}

// ---- 1. prep: src f32->bf16 + W transpose + zero cnt + zero-row ----
__global__ __launch_bounds__(256) void prep_kernel(
    const float* __restrict__ src_rep, unsigned short* __restrict__ srcb,
    const float* __restrict__ W, unsigned short* __restrict__ Wt,
    int* __restrict__ cnt) {
    if (blockIdx.x < CONV_BLOCKS) {
        size_t t = (size_t)blockIdx.x * 256 + threadIdx.x;  // 4 f32 -> 4 bf16
        float4 v = reinterpret_cast<const float4*>(src_rep)[t];
        uint2 w;
        w.x = pk(v.x, v.y); w.y = pk(v.z, v.w);
        reinterpret_cast<uint2*>(srcb)[t] = w;
    } else {
        int t = (blockIdx.x - CONV_BLOCKS) * 256 + threadIdx.x;
        if (t < 2 * D * D) {
            int n = t >> 8, k = t & 255;
            Wt[n * 256 + k] = f2bf(W[(size_t)k * D + n]);
        }
        int c = t - 2 * D * D;
        if (c >= 0 && c < N_DST) cnt[c] = 0;
        int z = c - N_DST;
        if (z >= 0 && z < D) srcb[(size_t)N_SRC * D + z] = 0;  // zero row
    }
}

// ---- 2. fill padded CSR: perm[d*PAD + slot] = src ----
__global__ __launch_bounds__(256) void fill_kernel(
    const int* __restrict__ edge_src, const int* __restrict__ edge_dst,
    int* __restrict__ cnt, int* __restrict__ perm) {
    int e = blockIdx.x * 256 + threadIdx.x;
    if (e < N_EDGES) {
        int d = edge_dst[e];
        int pos = atomicAdd(&cnt[d], 1);
        if (pos < PAD) perm[d * PAD + pos] = edge_src[e];
    }
}

// ---- 3. fused DMA-gather + MFMA GEMM + relu ----
// 512 threads = 8 waves; 16 dst rows/block; wave w owns rows 2w, 2w+1.
// Per 8-edge round: 4 global_load_lds (2 per row, 1KB each, per-lane global
// addr, ZERO VGPR in flight) -> one vmcnt(0) drain -> 4 ds_read_b128 + unpack
// per lane pair. dst_rep staging overlaps the first DMA round's latency.
// Invalid edge slots redirect to the zero row (branch-free, r10-verified).
__global__ __launch_bounds__(512) void fused_kernel(
    const unsigned short* __restrict__ srcb,   // [N_SRC+1][D] bf16 (last row 0)
    const float* __restrict__ dst_rep,
    const int*   __restrict__ cnt,
    const int*   __restrict__ perm,
    const unsigned short* __restrict__ Wt,     // [D][2*D] bf16, k-contiguous
    const float* __restrict__ bias,
    float*       __restrict__ out) {
    __shared__ __align__(16) unsigned short stage[8][2][1024];  // 32 KiB
    __shared__ unsigned short Abf[16 * 256];                    // 8 KiB
    const int row0 = blockIdx.x * 16;
    const int tid = threadIdx.x, lane = tid & 63, wave = tid >> 6;
    const int q = lane >> 4, cl = lane & 15;

    // prologue: cnt + perm loads first (critical path for gather)
    const int dn0 = row0 + wave * 2;
    const int2 cc = *reinterpret_cast<const int2*>(&cnt[dn0]);
    const int dmA = min(cc.x, PAD) - 1, dmB = min(cc.y, PAD) - 1;  // may be -1
    const int dcA = max(dmA, 0), dcB = max(dmB, 0);
    const int piA = perm[(size_t)dn0 * PAD + min(lane, PAD - 1)];
    const int piB = perm[(size_t)(dn0 + 1) * PAD + min(lane, PAD - 1)];
    const int rounds = (max(dmA, dmB) + 8) >> 3;   // ceil(maxdeg/8), 0 if both empty

    // stage dst_rep -> bf16 (k in [0,128)) — fills DMA/perm latency shadow
    if (tid < 256) {
        int r = tid >> 4, b = tid & 15;
        const float4* p = reinterpret_cast<const float4*>(
            dst_rep + (size_t)(row0 + r) * D + b * 8);
        float4 v0 = p[0], v1 = p[1];
        uint4 w;
        w.x = pk(v0.x, v0.y); w.y = pk(v0.z, v0.w);
        w.z = pk(v1.x, v1.y); w.w = pk(v1.z, v1.w);
        *reinterpret_cast<uint4*>(&Abf[r * 256 + (b ^ (r & 7)) * 8]) = w;
    }

    unsigned short* stA = stage[wave][0];
    unsigned short* stB = stage[wave][1];
    float accA[8] = {}, accB[8] = {};
    for (int rd = 0; rd < rounds; ++rd) {   // wave-uniform bound
        const int base = rd * 8;
        // issue 4 DMA loads: instr k covers edges base+4k+q for each row
#pragma unroll
        for (int k = 0; k < 2; ++k) {
            int e = base + 4 * k + q;
            int rA = __shfl(piA, min(e, dcA)); rA = (e <= dmA) ? rA : N_SRC;
            int rB = __shfl(piB, min(e, dcB)); rB = (e <= dmB) ? rB : N_SRC;
            __builtin_amdgcn_global_load_lds(
                (const unsigned int*)(srcb + (size_t)rA * D + cl * 8),
                (unsigned int*)(stA + k * 512), 16, 0, 0);
            __builtin_amdgcn_global_load_lds(
                (const unsigned int*)(srcb + (size_t)rB * D + cl * 8),
                (unsigned int*)(stB + k * 512), 16, 0, 0);
        }
        asm volatile("s_waitcnt vmcnt(0)" ::: "memory");
        __builtin_amdgcn_sched_barrier(0);
        // lane (q,cl): edges 4k+q of each row, slice cl
#pragma unroll
        for (int k = 0; k < 2; ++k) {
            uint4 uA = *reinterpret_cast<const uint4*>(stA + k * 512 + q * 128 + cl * 8);
            uint4 uB = *reinterpret_cast<const uint4*>(stB + k * 512 + q * 128 + cl * 8);
            addpk(accA, uA); addpk(accB, uB);
        }
        // fence staging WAR before next round's DMA overwrites it
        asm volatile("s_waitcnt lgkmcnt(0)" ::: "memory");
        __builtin_amdgcn_sched_barrier(0);
    }

    // cross-quarter reduce; lanes<16 hold the row sums (slice cl)
#pragma unroll
    for (int i = 0; i < 8; ++i) {
        accA[i] += __shfl_xor(accA[i], 16);
        accA[i] += __shfl_xor(accA[i], 32);
        accB[i] += __shfl_xor(accB[i], 16);
        accB[i] += __shfl_xor(accB[i], 32);
    }
    if (lane < 16) {
        const int rA = wave * 2, rB = wave * 2 + 1;
        uint4 w0, w1;
        w0.x = pk(accA[0], accA[1]); w0.y = pk(accA[2], accA[3]);
        w0.z = pk(accA[4], accA[5]); w0.w = pk(accA[6], accA[7]);
        w1.x = pk(accB[0], accB[1]); w1.y = pk(accB[2], accB[3]);
        w1.z = pk(accB[4], accB[5]); w1.w = pk(accB[6], accB[7]);
        *reinterpret_cast<uint4*>(&Abf[rA * 256 + ((16 + cl) ^ (rA & 7)) * 8]) = w0;
        *reinterpret_cast<uint4*>(&Abf[rB * 256 + ((16 + cl) ^ (rB & 7)) * 8]) = w1;
    }
    __syncthreads();

    // MFMA: A 16x256 (LDS) x B 256x16 per wave; wave w -> out cols [16w,16w+16)
    f32x4 c0 = {0.f, 0.f, 0.f, 0.f};
    const int ar = lane & 15;
    const int kb = lane >> 4;
    const int n0 = wave * 16 + (lane & 15);
#pragma unroll
    for (int s = 0; s < 8; ++s) {
        int b = s * 4 + kb;
        bf16x8 af = *reinterpret_cast<const bf16x8*>(&Abf[ar * 256 + (b ^ (ar & 7)) * 8]);
        bf16x8 b0 = *reinterpret_cast<const bf16x8*>(&Wt[(size_t)n0 * 256 + s * 32 + kb * 8]);
        c0 = __builtin_amdgcn_mfma_f32_16x16x32_bf16(af, b0, c0, 0, 0, 0);
    }

    const float bv = bias[n0];
#pragma unroll
    for (int g = 0; g < 4; ++g) {
        size_t orow = row0 + (lane >> 4) * 4 + g;
        out[orow * D + n0] = fmaxf(c0[g] + bv, 0.f);
    }
}

// ---- fallback path (small ws): round-6 verified kernels ----
__global__ __launch_bounds__(256) void prep_small_kernel(
    const float* __restrict__ W, unsigned short* __restrict__ Wt,
    int* __restrict__ cnt) {
    int t = blockIdx.x * 256 + threadIdx.x;
    if (t < 2 * D * D) {
        int n = t >> 8, k = t & 255;
        Wt[n * 256 + k] = f2bf(W[(size_t)k * D + n]);
    }
    int c = t - 2 * D * D;
    if (c >= 0 && c < N_DST) cnt[c] = 0;
}

__global__ __launch_bounds__(256) void gather_f32_kernel(
    const float* __restrict__ src_rep,
    const int*   __restrict__ cnt,
    const int*   __restrict__ perm,
    unsigned short* __restrict__ agg) {
    const int tid = threadIdx.x, lane = tid & 63, wave = tid >> 6;
    const int h = lane >> 5, c = lane & 31;
    const int dn = blockIdx.x * 4 + wave;
    const int deg = min(cnt[dn], PAD);
    const int pi = perm[(size_t)dn * PAD + min(lane, PAD - 1)];

    f32x4 a0 = {0.f, 0.f, 0.f, 0.f}, a1 = a0, a2 = a0, a3 = a0;
    const int dm1 = deg - 1;
    for (int base = 0; base < deg; base += 8) {
        int e0 = base + h, e1 = base + 2 + h, e2 = base + 4 + h, e3 = base + 6 + h;
        int s0 = __shfl(pi, min(e0, max(dm1, 0)));
        int s1 = __shfl(pi, min(e1, max(dm1, 0)));
        int s2 = __shfl(pi, min(e2, max(dm1, 0)));
        int s3 = __shfl(pi, min(e3, max(dm1, 0)));
        if (e0 <= dm1) a0 += *reinterpret_cast<const f32x4*>(src_rep + (size_t)s0 * D + c * 4);
        if (e1 <= dm1) a1 += *reinterpret_cast<const f32x4*>(src_rep + (size_t)s1 * D + c * 4);
        if (e2 <= dm1) a2 += *reinterpret_cast<const f32x4*>(src_rep + (size_t)s2 * D + c * 4);
        if (e3 <= dm1) a3 += *reinterpret_cast<const f32x4*>(src_rep + (size_t)s3 * D + c * 4);
    }
    a0 += a1; a2 += a3; a0 += a2;
#pragma unroll
    for (int qq = 0; qq < 4; ++qq) a0[qq] += __shfl_xor(a0[qq], 32);
    if (h == 0) {
        uint2 w;
        w.x = pk(a0[0], a0[1]); w.y = pk(a0[2], a0[3]);
        *reinterpret_cast<uint2*>(agg + (size_t)dn * D + c * 4) = w;
    }
}

__global__ __launch_bounds__(256) void gemm_kernel(
    const float* __restrict__ dst_rep,
    const unsigned short* __restrict__ agg,
    const unsigned short* __restrict__ Wt,
    const float* __restrict__ bias,
    float*       __restrict__ out) {
    __shared__ unsigned short Abf[RPB * 2 * D];
    const int row0 = blockIdx.x * RPB;
    const int tid = threadIdx.x, lane = tid & 63, wave = tid >> 6;
    {
        int r = tid >> 4, b = tid & 15;
        const float4* p = reinterpret_cast<const float4*>(
            dst_rep + (size_t)(row0 + r) * D + b * 8);
        float4 v0 = p[0], v1 = p[1];
        uint4 w;
        w.x = pk(v0.x, v0.y); w.y = pk(v0.z, v0.w);
        w.z = pk(v1.x, v1.y); w.w = pk(v1.z, v1.w);
        *reinterpret_cast<uint4*>(&Abf[r * 256 + (b ^ (r & 7)) * 8]) = w;
        uint4 g = *reinterpret_cast<const uint4*>(agg + (size_t)(row0 + r) * D + b * 8);
        *reinterpret_cast<uint4*>(&Abf[r * 256 + ((16 + b) ^ (r & 7)) * 8]) = g;
    }
    __syncthreads();

    f32x4 c0 = {0.f, 0.f, 0.f, 0.f}, c1 = {0.f, 0.f, 0.f, 0.f};
    const int ar = lane & 15;
    const int kb = lane >> 4;
    const int n0 = wave * 32 + (lane & 15);
#pragma unroll
    for (int s = 0; s < 8; ++s) {
        int b = s * 4 + kb;
        bf16x8 af = *reinterpret_cast<const bf16x8*>(&Abf[ar * 256 + (b ^ (ar & 7)) * 8]);
        int kbase = s * 32 + kb * 8;
        bf16x8 b0 = *reinterpret_cast<const bf16x8*>(&Wt[(size_t)n0 * 256 + kbase]);
        bf16x8 b1 = *reinterpret_cast<const bf16x8*>(&Wt[(size_t)(n0 + 16) * 256 + kbase]);
        c0 = __builtin_amdgcn_mfma_f32_16x16x32_bf16(af, b0, c0, 0, 0, 0);
        c1 = __builtin_amdgcn_mfma_f32_16x16x32_bf16(af, b1, c1, 0, 0, 0);
    }
    const float bv0 = bias[wave * 32 + (lane & 15)];
    const float bv1 = bias[wave * 32 + 16 + (lane & 15)];
#pragma unroll
    for (int g = 0; g < 4; ++g) {
        size_t orow = row0 + (lane >> 4) * 4 + g;
        out[orow * D + wave * 32 + (lane & 15)]      = fmaxf(c0[g] + bv0, 0.f);
        out[orow * D + wave * 32 + 16 + (lane & 15)] = fmaxf(c1[g] + bv1, 0.f);
    }
}

extern "C" void kernel_launch(void* const* d_in, const int* in_sizes, int n_in,
                              void* d_out, int out_size, void* d_ws, size_t ws_size,
                              hipStream_t stream) {
    const float* src_rep  = (const float*)d_in[0];
    const float* dst_rep  = (const float*)d_in[1];
    const int*   edge_src = (const int*)d_in[2];
    const int*   edge_dst = (const int*)d_in[3];
    const float* W        = (const float*)d_in[4];
    const float* bias     = (const float*)d_in[5];
    float*       out      = (float*)d_out;

    // ws: cnt[N_DST] | perm[N_DST*PAD] | Wt[2*D*D] | {srcb[(N_SRC+1)*D] or agg}
    int* cnt  = (int*)d_ws;
    int* perm = cnt + N_DST;
    size_t wt_off = (((size_t)N_DST * (1 + PAD) * 4 + 255) / 256) * 256;
    unsigned short* Wt   = (unsigned short*)((char*)d_ws + wt_off);
    unsigned short* big  = Wt + (size_t)2 * D * D;   // srcb or agg
    const size_t need_full = wt_off + ((size_t)2 * D * D + (size_t)(N_SRC + 1) * D)
                             * sizeof(unsigned short);

    if (ws_size >= need_full) {
        unsigned short* srcb = big;
        prep_kernel<<<CONV_BLOCKS + MISC_BLOCKS, 256, 0, stream>>>(
            src_rep, srcb, W, Wt, cnt);
        fill_kernel<<<FILL_BLOCKS, 256, 0, stream>>>(edge_src, edge_dst, cnt, perm);
        fused_kernel<<<N_DST / 16, 512, 0, stream>>>(
            srcb, dst_rep, cnt, perm, Wt, bias, out);
    } else {
        unsigned short* agg = big;
        prep_small_kernel<<<MISC_BLOCKS, 256, 0, stream>>>(W, Wt, cnt);
        fill_kernel<<<FILL_BLOCKS, 256, 0, stream>>>(edge_src, edge_dst, cnt, perm);
        gather_f32_kernel<<<N_DST / 4, 256, 0, stream>>>(src_rep, cnt, perm, agg);
        gemm_kernel<<<N_DST / RPB, 256, 0, stream>>>(dst_rep, agg, Wt, bias, out);
    }
}

// Round 14
// 98.526 us; speedup vs baseline: 6.3574x; 1.0213x over previous
//
#include <hip/hip_runtime.h>

#define N_SRC   100000
#define N_DST   50000
#define N_EDGES 600000
#define D       128
#define RPB     16    // dst rows per block (fallback GEMM)
#define PAD     48    // padded CSR slots per dst (verified r4-r13: no overflow)

#define CONV_BLOCKS  ((N_SRC * D / 4) / 256)          // 12500 (4 f32/thread)
#define MISC_ELEMS   (2 * D * D + N_DST + D)          // Wt + cnt + zero-row
#define MISC_BLOCKS  ((MISC_ELEMS + 255) / 256)
#define FILL_BLOCKS  ((N_EDGES / 2 + 255) / 256)      // 1172 (2 edges/thread)

typedef short bf16x8 __attribute__((ext_vector_type(8)));
typedef float f32x4  __attribute__((ext_vector_type(4)));

static __device__ __forceinline__ unsigned short f2bf(float f) {
    unsigned u = __float_as_uint(f);
    u += 0x7FFF + ((u >> 16) & 1);  // RNE
    return (unsigned short)(u >> 16);
}
static __device__ __forceinline__ unsigned pk(float a, float b) {
    return (unsigned)f2bf(a) | ((unsigned)f2bf(b) << 16);
}
// accumulate 8 bf16 (uint4) into 8 f32
static __device__ __forceinline__ void addpk(float* a, uint4 u) {
    a[0] += __uint_as_float(u.x << 16);
    a[1] += __uint_as_float(u.x & 0xFFFF0000u);
    a[2] += __uint_as_float(u.y << 16);
    a[3] += __uint_as_float(u.y & 0xFFFF0000u);
    a[4] += __uint_as_float(u.z << 16);
    a[5] += __uint_as_float(u.z & 0xFFFF0000u);
    a[6] += __uint_as_float(u.w << 16);
    a[7] += __uint_as_float(u.w & 0xFFFF0000u);
}

// ---- 1. prep: src f32->bf16 + W transpose + zero cnt + zero-row ----
__global__ __launch_bounds__(256) void prep_kernel(
    const float* __restrict__ src_rep, unsigned short* __restrict__ srcb,
    const float* __restrict__ W, unsigned short* __restrict__ Wt,
    int* __restrict__ cnt) {
    if (blockIdx.x < CONV_BLOCKS) {
        size_t t = (size_t)blockIdx.x * 256 + threadIdx.x;  // 4 f32 -> 4 bf16
        float4 v = reinterpret_cast<const float4*>(src_rep)[t];
        uint2 w;
        w.x = pk(v.x, v.y); w.y = pk(v.z, v.w);
        reinterpret_cast<uint2*>(srcb)[t] = w;
    } else {
        int t = (blockIdx.x - CONV_BLOCKS) * 256 + threadIdx.x;
        if (t < 2 * D * D) {
            int n = t >> 8, k = t & 255;
            Wt[n * 256 + k] = f2bf(W[(size_t)k * D + n]);
        }
        int c = t - 2 * D * D;
        if (c >= 0 && c < N_DST) cnt[c] = 0;
        int z = c - N_DST;
        if (z >= 0 && z < D) srcb[(size_t)N_SRC * D + z] = 0;  // zero row
    }
}

// ---- 2. fill padded CSR: perm[d*PAD + slot] = src (2 edges/thread) ----
__global__ __launch_bounds__(256) void fill_kernel(
    const int* __restrict__ edge_src, const int* __restrict__ edge_dst,
    int* __restrict__ cnt, int* __restrict__ perm) {
    int e0 = (blockIdx.x * 256 + threadIdx.x) * 2;
    if (e0 < N_EDGES) {  // N_EDGES even -> e0+1 also valid
        int2 s2 = *reinterpret_cast<const int2*>(edge_src + e0);
        int2 d2 = *reinterpret_cast<const int2*>(edge_dst + e0);
        int p0 = atomicAdd(&cnt[d2.x], 1);
        if (p0 < PAD) perm[d2.x * PAD + p0] = s2.x;
        int p1 = atomicAdd(&cnt[d2.y], 1);
        if (p1 < PAD) perm[d2.y * PAD + p1] = s2.y;
    }
}

// ---- 3. fused pipelined-DMA gather + MFMA GEMM + relu ----
// 512 threads = 8 waves; 16 dst rows/block; wave w owns rows 2w, 2w+1.
// 4-edge rounds (1 DMA per row per round, 1KB each), 2-slot double buffer,
// counted vmcnt(2): round rd+1 stays in flight while consuming round rd.
// Invalid edge slots redirect to the zero row (branch-free, r10-verified).
__global__ __launch_bounds__(512) void fused_kernel(
    const unsigned short* __restrict__ srcb,   // [N_SRC+1][D] bf16 (last row 0)
    const float* __restrict__ dst_rep,
    const int*   __restrict__ cnt,
    const int*   __restrict__ perm,
    const unsigned short* __restrict__ Wt,     // [D][2*D] bf16, k-contiguous
    const float* __restrict__ bias,
    float*       __restrict__ out) {
    __shared__ __align__(16) unsigned short stage[8][2][2][512];  // 32 KiB
    __shared__ unsigned short Abf[16 * 256];                      // 8 KiB
    const int row0 = blockIdx.x * 16;
    const int tid = threadIdx.x, lane = tid & 63, wave = tid >> 6;
    const int q = lane >> 4, cl = lane & 15;

    // prologue: cnt + perm loads first (critical path for gather)
    const int dn0 = row0 + wave * 2;
    const int2 cc = *reinterpret_cast<const int2*>(&cnt[dn0]);
    const int dmA = min(cc.x, PAD) - 1, dmB = min(cc.y, PAD) - 1;  // may be -1
    const int dcA = max(dmA, 0), dcB = max(dmB, 0);
    const int piA = perm[(size_t)dn0 * PAD + min(lane, PAD - 1)];
    const int piB = perm[(size_t)(dn0 + 1) * PAD + min(lane, PAD - 1)];
    const int rounds = (max(dmA, dmB) + 4) >> 2;   // ceil(maxdeg/4); 0 if empty

    // stage dst_rep -> bf16 (k in [0,128))
    if (tid < 256) {
        int r = tid >> 4, b = tid & 15;
        const float4* p = reinterpret_cast<const float4*>(
            dst_rep + (size_t)(row0 + r) * D + b * 8);
        float4 v0 = p[0], v1 = p[1];
        uint4 w;
        w.x = pk(v0.x, v0.y); w.y = pk(v0.z, v0.w);
        w.z = pk(v1.x, v1.y); w.w = pk(v1.z, v1.w);
        *reinterpret_cast<uint4*>(&Abf[r * 256 + (b ^ (r & 7)) * 8]) = w;
    }

    float accA[8] = {}, accB[8] = {};
    auto ISSUE = [&](int rd, int slot) {
        int e = rd * 4 + q;
        int rA = __shfl(piA, min(e, dcA)); rA = (e <= dmA) ? rA : N_SRC;
        int rB = __shfl(piB, min(e, dcB)); rB = (e <= dmB) ? rB : N_SRC;
        __builtin_amdgcn_global_load_lds(
            (const unsigned int*)(srcb + (size_t)rA * D + cl * 8),
            (unsigned int*)(&stage[wave][slot][0][0]), 16, 0, 0);
        __builtin_amdgcn_global_load_lds(
            (const unsigned int*)(srcb + (size_t)rB * D + cl * 8),
            (unsigned int*)(&stage[wave][slot][1][0]), 16, 0, 0);
    };
    auto CONSUME = [&](int slot) {
        uint4 uA = *reinterpret_cast<const uint4*>(&stage[wave][slot][0][q * 128 + cl * 8]);
        uint4 uB = *reinterpret_cast<const uint4*>(&stage[wave][slot][1][q * 128 + cl * 8]);
        addpk(accA, uA); addpk(accB, uB);
    };

    if (rounds > 0) {
        ISSUE(0, 0);
        for (int rd = 0; rd + 1 < rounds; ++rd) {   // wave-uniform bound
            ISSUE(rd + 1, (rd + 1) & 1);
            asm volatile("s_waitcnt vmcnt(2)" ::: "memory");  // round rd done
            __builtin_amdgcn_sched_barrier(0);
            CONSUME(rd & 1);
            asm volatile("s_waitcnt lgkmcnt(0)" ::: "memory"); // ds_reads done (WAR)
            __builtin_amdgcn_sched_barrier(0);
        }
        asm volatile("s_waitcnt vmcnt(0)" ::: "memory");
        __builtin_amdgcn_sched_barrier(0);
        CONSUME((rounds - 1) & 1);
    }

    // cross-quarter reduce; lanes<16 hold the row sums (slice cl)
#pragma unroll
    for (int i = 0; i < 8; ++i) {
        accA[i] += __shfl_xor(accA[i], 16);
        accA[i] += __shfl_xor(accA[i], 32);
        accB[i] += __shfl_xor(accB[i], 16);
        accB[i] += __shfl_xor(accB[i], 32);
    }
    if (lane < 16) {
        const int rA = wave * 2, rB = wave * 2 + 1;
        uint4 w0, w1;
        w0.x = pk(accA[0], accA[1]); w0.y = pk(accA[2], accA[3]);
        w0.z = pk(accA[4], accA[5]); w0.w = pk(accA[6], accA[7]);
        w1.x = pk(accB[0], accB[1]); w1.y = pk(accB[2], accB[3]);
        w1.z = pk(accB[4], accB[5]); w1.w = pk(accB[6], accB[7]);
        *reinterpret_cast<uint4*>(&Abf[rA * 256 + ((16 + cl) ^ (rA & 7)) * 8]) = w0;
        *reinterpret_cast<uint4*>(&Abf[rB * 256 + ((16 + cl) ^ (rB & 7)) * 8]) = w1;
    }
    __syncthreads();

    // MFMA: A 16x256 (LDS) x B 256x16 per wave; wave w -> out cols [16w,16w+16)
    f32x4 c0 = {0.f, 0.f, 0.f, 0.f};
    const int ar = lane & 15;
    const int kb = lane >> 4;
    const int n0 = wave * 16 + (lane & 15);
#pragma unroll
    for (int s = 0; s < 8; ++s) {
        int b = s * 4 + kb;
        bf16x8 af = *reinterpret_cast<const bf16x8*>(&Abf[ar * 256 + (b ^ (ar & 7)) * 8]);
        bf16x8 b0 = *reinterpret_cast<const bf16x8*>(&Wt[(size_t)n0 * 256 + s * 32 + kb * 8]);
        c0 = __builtin_amdgcn_mfma_f32_16x16x32_bf16(af, b0, c0, 0, 0, 0);
    }

    const float bv = bias[n0];
#pragma unroll
    for (int g = 0; g < 4; ++g) {
        size_t orow = row0 + (lane >> 4) * 4 + g;
        out[orow * D + n0] = fmaxf(c0[g] + bv, 0.f);
    }
}

// ---- fallback path (small ws): round-6 verified kernels ----
__global__ __launch_bounds__(256) void prep_small_kernel(
    const float* __restrict__ W, unsigned short* __restrict__ Wt,
    int* __restrict__ cnt) {
    int t = blockIdx.x * 256 + threadIdx.x;
    if (t < 2 * D * D) {
        int n = t >> 8, k = t & 255;
        Wt[n * 256 + k] = f2bf(W[(size_t)k * D + n]);
    }
    int c = t - 2 * D * D;
    if (c >= 0 && c < N_DST) cnt[c] = 0;
}

__global__ __launch_bounds__(256) void gather_f32_kernel(
    const float* __restrict__ src_rep,
    const int*   __restrict__ cnt,
    const int*   __restrict__ perm,
    unsigned short* __restrict__ agg) {
    const int tid = threadIdx.x, lane = tid & 63, wave = tid >> 6;
    const int h = lane >> 5, c = lane & 31;
    const int dn = blockIdx.x * 4 + wave;
    const int deg = min(cnt[dn], PAD);
    const int pi = perm[(size_t)dn * PAD + min(lane, PAD - 1)];

    f32x4 a0 = {0.f, 0.f, 0.f, 0.f}, a1 = a0, a2 = a0, a3 = a0;
    const int dm1 = deg - 1;
    for (int base = 0; base < deg; base += 8) {
        int e0 = base + h, e1 = base + 2 + h, e2 = base + 4 + h, e3 = base + 6 + h;
        int s0 = __shfl(pi, min(e0, max(dm1, 0)));
        int s1 = __shfl(pi, min(e1, max(dm1, 0)));
        int s2 = __shfl(pi, min(e2, max(dm1, 0)));
        int s3 = __shfl(pi, min(e3, max(dm1, 0)));
        if (e0 <= dm1) a0 += *reinterpret_cast<const f32x4*>(src_rep + (size_t)s0 * D + c * 4);
        if (e1 <= dm1) a1 += *reinterpret_cast<const f32x4*>(src_rep + (size_t)s1 * D + c * 4);
        if (e2 <= dm1) a2 += *reinterpret_cast<const f32x4*>(src_rep + (size_t)s2 * D + c * 4);
        if (e3 <= dm1) a3 += *reinterpret_cast<const f32x4*>(src_rep + (size_t)s3 * D + c * 4);
    }
    a0 += a1; a2 += a3; a0 += a2;
#pragma unroll
    for (int qq = 0; qq < 4; ++qq) a0[qq] += __shfl_xor(a0[qq], 32);
    if (h == 0) {
        uint2 w;
        w.x = pk(a0[0], a0[1]); w.y = pk(a0[2], a0[3]);
        *reinterpret_cast<uint2*>(agg + (size_t)dn * D + c * 4) = w;
    }
}

__global__ __launch_bounds__(256) void gemm_kernel(
    const float* __restrict__ dst_rep,
    const unsigned short* __restrict__ agg,
    const unsigned short* __restrict__ Wt,
    const float* __restrict__ bias,
    float*       __restrict__ out) {
    __shared__ unsigned short Abf[RPB * 2 * D];
    const int row0 = blockIdx.x * RPB;
    const int tid = threadIdx.x, lane = tid & 63, wave = tid >> 6;
    {
        int r = tid >> 4, b = tid & 15;
        const float4* p = reinterpret_cast<const float4*>(
            dst_rep + (size_t)(row0 + r) * D + b * 8);
        float4 v0 = p[0], v1 = p[1];
        uint4 w;
        w.x = pk(v0.x, v0.y); w.y = pk(v0.z, v0.w);
        w.z = pk(v1.x, v1.y); w.w = pk(v1.z, v1.w);
        *reinterpret_cast<uint4*>(&Abf[r * 256 + (b ^ (r & 7)) * 8]) = w;
        uint4 g = *reinterpret_cast<const uint4*>(agg + (size_t)(row0 + r) * D + b * 8);
        *reinterpret_cast<uint4*>(&Abf[r * 256 + ((16 + b) ^ (r & 7)) * 8]) = g;
    }
    __syncthreads();

    f32x4 c0 = {0.f, 0.f, 0.f, 0.f}, c1 = {0.f, 0.f, 0.f, 0.f};
    const int ar = lane & 15;
    const int kb = lane >> 4;
    const int n0 = wave * 32 + (lane & 15);
#pragma unroll
    for (int s = 0; s < 8; ++s) {
        int b = s * 4 + kb;
        bf16x8 af = *reinterpret_cast<const bf16x8*>(&Abf[ar * 256 + (b ^ (ar & 7)) * 8]);
        int kbase = s * 32 + kb * 8;
        bf16x8 b0 = *reinterpret_cast<const bf16x8*>(&Wt[(size_t)n0 * 256 + kbase]);
        bf16x8 b1 = *reinterpret_cast<const bf16x8*>(&Wt[(size_t)(n0 + 16) * 256 + kbase]);
        c0 = __builtin_amdgcn_mfma_f32_16x16x32_bf16(af, b0, c0, 0, 0, 0);
        c1 = __builtin_amdgcn_mfma_f32_16x16x32_bf16(af, b1, c1, 0, 0, 0);
    }
    const float bv0 = bias[wave * 32 + (lane & 15)];
    const float bv1 = bias[wave * 32 + 16 + (lane & 15)];
#pragma unroll
    for (int g = 0; g < 4; ++g) {
        size_t orow = row0 + (lane >> 4) * 4 + g;
        out[orow * D + wave * 32 + (lane & 15)]      = fmaxf(c0[g] + bv0, 0.f);
        out[orow * D + wave * 32 + 16 + (lane & 15)] = fmaxf(c1[g] + bv1, 0.f);
    }
}

extern "C" void kernel_launch(void* const* d_in, const int* in_sizes, int n_in,
                              void* d_out, int out_size, void* d_ws, size_t ws_size,
                              hipStream_t stream) {
    const float* src_rep  = (const float*)d_in[0];
    const float* dst_rep  = (const float*)d_in[1];
    const int*   edge_src = (const int*)d_in[2];
    const int*   edge_dst = (const int*)d_in[3];
    const float* W        = (const float*)d_in[4];
    const float* bias     = (const float*)d_in[5];
    float*       out      = (float*)d_out;

    // ws: cnt[N_DST] | perm[N_DST*PAD] | Wt[2*D*D] | {srcb[(N_SRC+1)*D] or agg}
    int* cnt  = (int*)d_ws;
    int* perm = cnt + N_DST;
    size_t wt_off = (((size_t)N_DST * (1 + PAD) * 4 + 255) / 256) * 256;
    unsigned short* Wt   = (unsigned short*)((char*)d_ws + wt_off);
    unsigned short* big  = Wt + (size_t)2 * D * D;   // srcb or agg
    const size_t need_full = wt_off + ((size_t)2 * D * D + (size_t)(N_SRC + 1) * D)
                             * sizeof(unsigned short);

    if (ws_size >= need_full) {
        unsigned short* srcb = big;
        prep_kernel<<<CONV_BLOCKS + MISC_BLOCKS, 256, 0, stream>>>(
            src_rep, srcb, W, Wt, cnt);
        fill_kernel<<<FILL_BLOCKS, 256, 0, stream>>>(edge_src, edge_dst, cnt, perm);
        fused_kernel<<<N_DST / 16, 512, 0, stream>>>(
            srcb, dst_rep, cnt, perm, Wt, bias, out);
    } else {
        unsigned short* agg = big;
        prep_small_kernel<<<MISC_BLOCKS, 256, 0, stream>>>(W, Wt, cnt);
        fill_kernel<<<FILL_BLOCKS, 256, 0, stream>>>(edge_src, edge_dst, cnt, perm);
        gather_f32_kernel<<<N_DST / 4, 256, 0, stream>>>(src_rep, cnt, perm, agg);
        gemm_kernel<<<N_DST / RPB, 256, 0, stream>>>(dst_rep, agg, Wt, bias, out);
    }
}